// Round 10
// baseline (185.379 us; speedup 1.0000x reference)
//
#include <hip/hip_runtime.h>

// PlateYoloBlock: (32,13,256,256) fp32 -> (32,65536,13) fp32
// out[b][y*256+x][c]:
//   c=0: (sigmoid(v)+x)*8   c=1: (sigmoid(v)+y)*8
//   c=2,3: exp(v)*8         c=4..11: v*8          c=12: sigmoid(v)
//
// v9: DRAM RUN-LENGTH probe. nt loads were the only winner in 9 rounds
// (65.2 -> ~63.5us) -> the wall is memory-side stream presentation, not
// CU machinery. Last untried axis: per-channel contiguous run length
// (was 2-4KB in every variant; copy kernels that hit 6.3 TB/s present
// long runs). v9: TILE=4096 positions/block (512 blocks, 2/CU, 8
// waves/CU) -> each of the 13 channel-streams is 16KB contiguous,
// swept in temporal order via 4 sub-tiles of the proven v8 body.
// nt on loads (winner) and stores (null, keeps MALL bypassed) retained.
// Sub-tile t+1's loads issue before t's barriers drain (no LDS dep).

#define NB      32
#define NC      13
#define HW      65536     // 256*256 positions per batch
#define WIDTH   256
#define THREADS 256
#define PPT     4         // positions per thread per sub-tile
#define SUB     (THREADS * PPT)        // 1024 positions per sub-tile
#define NSUB    4
#define TILE    (SUB * NSUB)           // 4096 positions per block
#define NBLOCKS ((NB * HW) / TILE)     // 512

typedef float v4f __attribute__((ext_vector_type(4)));

__device__ __forceinline__ float sigmoidf_(float x) {
    return 1.0f / (1.0f + __expf(-x));
}

__global__ __launch_bounds__(THREADS) void plate_yolo_kernel(
        const float* __restrict__ in, float* __restrict__ out) {
    __shared__ float lds[SUB * NC];    // 53,248 B -> 2 blocks/CU possible; 1 needed

    const int tid = threadIdx.x;
    const long long s0 = (long long)blockIdx.x * TILE;   // global spatial base
    const int b = (int)(s0 >> 16);                       // tile within one batch
    const int posBase = (int)(s0 & (HW - 1));
    const float* __restrict__ inB = in + (long long)b * NC * HW + posBase;

    #pragma unroll
    for (int t = 0; t < NSUB; ++t) {
        const int p0   = t * SUB + tid * PPT;    // 4 consecutive positions
        const int pos0 = posBase + p0;
        const float fx0 = (float)(pos0 & (WIDTH - 1));  // row not crossed in quad
        const float fy  = (float)(pos0 >> 8);

        // Phase A: 13 nt dwordx4 loads. No LDS dependence -> compiler
        // hoists them above the trailing barrier of iteration t-1.
        v4f v[NC];
        #pragma unroll
        for (int c = 0; c < NC; ++c) {
            v[c] = __builtin_nontemporal_load((const v4f*)(inB + c * HW + p0));
        }

        // Phase B: pointwise math into output-layout register block.
        float res[PPT * NC];               // res[q*13 + c], static indices
        #pragma unroll
        for (int c = 0; c < NC; ++c) {
            #pragma unroll
            for (int q = 0; q < PPT; ++q) {
                const float x = v[c][q];
                float r;
                if (c == 0)                 r = (sigmoidf_(x) + (fx0 + (float)q)) * 8.0f;
                else if (c == 1)            r = (sigmoidf_(x) + fy) * 8.0f;
                else if (c == 2 || c == 3)  r = __expf(x) * 8.0f;
                else if (c == 12)           r = sigmoidf_(x);
                else                        r = x * 8.0f;
                res[q * NC + c] = r;
            }
        }

        // LDS reused across sub-tiles: ensure previous copy-out retired.
        if (t > 0) __syncthreads();

        // Phase C: 13 ds_write_b128 into thread's contiguous 52-float region
        // (proven v2 pattern; conflicts fully masked by memory time).
        v4f* __restrict__ ldsT = (v4f*)(lds + (tid * PPT) * NC);
        #pragma unroll
        for (int j = 0; j < NC; ++j) {
            v4f w;
            w[0] = res[4*j + 0]; w[1] = res[4*j + 1];
            w[2] = res[4*j + 2]; w[3] = res[4*j + 3];
            ldsT[j] = w;
        }
        __syncthreads();

        // Phase D: contiguous nt float4 copy-out (ds_read_b128 +
        // global_store_dwordx4 nt). Sub-tile base = (s0 + t*SUB)*13 floats.
        const v4f* __restrict__ src = (const v4f*)lds;
        v4f* __restrict__ dst = (v4f*)(out + (s0 + (long long)t * SUB) * NC);
        #pragma unroll
        for (int j = 0; j < NC; ++j) {
            __builtin_nontemporal_store(src[tid + j * THREADS],
                                        &dst[tid + j * THREADS]);
        }
    }
}

extern "C" void kernel_launch(void* const* d_in, const int* in_sizes, int n_in,
                              void* d_out, int out_size, void* d_ws, size_t ws_size,
                              hipStream_t stream) {
    const float* in = (const float*)d_in[0];
    float* out = (float*)d_out;
    plate_yolo_kernel<<<NBLOCKS, THREADS, 0, stream>>>(in, out);
}